// Round 1
// baseline (836.985 us; speedup 1.0000x reference)
//
#include <hip/hip_runtime.h>
#include <hip/hip_bf16.h>
#include <math.h>

// Problem constants (TransformerBlock: B=4,S=2048,D=1024,H=16,DFF=4096)
#define B_   4
#define S_   2048
#define D_   1024
#define H_   16
#define DK_  64
#define DFF_ 4096
#define M_   (B_*S_)   // 8192 rows

typedef __bf16 bf16;
typedef bf16 bf16x8 __attribute__((ext_vector_type(8)));
typedef bf16 bf16x4 __attribute__((ext_vector_type(4)));
typedef float f32x4 __attribute__((ext_vector_type(4)));

// ---- async global->LDS, 16B per lane, wave-uniform LDS base + lane*16 ----
__device__ __forceinline__ void g2lds16(const void* g, void* l) {
  __builtin_amdgcn_global_load_lds(
      (__attribute__((address_space(1))) void*)(void*)g,
      (__attribute__((address_space(3))) void*)l, 16, 0, 0);
}

// =====================================================================
// Weight cast + transpose: W[K][N] f32 -> Wt[N][K] bf16
// =====================================================================
__global__ void tcast(const float* __restrict__ W, bf16* __restrict__ Wt,
                      int K, int N) {
  __shared__ float t[32][33];
  int n0 = blockIdx.x * 32, k0 = blockIdx.y * 32;
  int tx = threadIdx.x, ty = threadIdx.y;
#pragma unroll
  for (int i = 0; i < 4; ++i)
    t[ty + i*8][tx] = W[(size_t)(k0 + ty + i*8) * N + n0 + tx];
  __syncthreads();
#pragma unroll
  for (int i = 0; i < 4; ++i)
    Wt[(size_t)(n0 + ty + i*8) * K + k0 + tx] = (bf16)t[tx][ty + i*8];
}

// =====================================================================
// LayerNorm over D=1024, one block (256 thr) per row, bf16 output
// =====================================================================
__global__ __launch_bounds__(256)
void ln_fwd(const float* __restrict__ x, const float* __restrict__ g,
            const float* __restrict__ be, bf16* __restrict__ out) {
  int row = blockIdx.x, tid = threadIdx.x;
  const float4 v = *(const float4*)&x[(size_t)row * D_ + tid * 4];
  float s = v.x + v.y + v.z + v.w;
  float q = v.x*v.x + v.y*v.y + v.z*v.z + v.w*v.w;
#pragma unroll
  for (int d = 32; d; d >>= 1) { s += __shfl_down(s, d); q += __shfl_down(q, d); }
  __shared__ float red[8];
  int wave = tid >> 6, lane = tid & 63;
  if (lane == 0) { red[wave*2] = s; red[wave*2+1] = q; }
  __syncthreads();
  float ts = red[0] + red[2] + red[4] + red[6];
  float tq = red[1] + red[3] + red[5] + red[7];
  float mean = ts * (1.0f / D_);
  float var  = tq * (1.0f / D_) - mean * mean;
  float rstd = rsqrtf(var + 1e-5f);
  const float4 gg = *(const float4*)&g[tid * 4];
  const float4 bb = *(const float4*)&be[tid * 4];
  bf16x4 ov;
  ov[0] = (bf16)((v.x - mean) * rstd * gg.x + bb.x);
  ov[1] = (bf16)((v.y - mean) * rstd * gg.y + bb.y);
  ov[2] = (bf16)((v.z - mean) * rstd * gg.z + bb.z);
  ov[3] = (bf16)((v.w - mean) * rstd * gg.w + bb.w);
  *(bf16x4*)&out[(size_t)row * D_ + tid * 4] = ov;
}

// =====================================================================
// GEMM: C[M,N] = A[M,K] @ Bt[N,K]^T  (both bf16 row-major, f32 acc)
// 128x128 tile, BK=32, 4 waves (2x2), 16x16x32 MFMA, global_load_lds.
// EPI 0: outb[B,H,S,DK] = (C + bias) * scale   (Q/K projection scatter)
// EPI 1: outf[row*N+col] = C + bias + resid    (residual add, f32 out)
// EPI 2: outb[row*N+col] = gelu_exact(C+bias)  (bf16 out)
// =====================================================================
template <int EPI>
__global__ __launch_bounds__(256)
void gemm_bt(const bf16* __restrict__ A, const bf16* __restrict__ Bt,
             int M, int N, int K,
             const float* __restrict__ bias, const float* __restrict__ resid,
             float scale, float* __restrict__ outf, bf16* __restrict__ outb) {
  __shared__ __align__(16) bf16 As[128 * 32];
  __shared__ __align__(16) bf16 Bs[128 * 32];
  const int tid = threadIdx.x;
  const int wave = tid >> 6, lane = tid & 63;
  const int wr = wave >> 1, wc = wave & 1;
  const long arow = (long)blockIdx.y * 128;
  const long bcol = (long)blockIdx.x * 128;

  f32x4 acc[4][4] = {};

  // staging coords: chunk = 1KB of LDS = 16 rows of 32 bf16; lane covers 16B
  const int c0 = wave * 2, c1 = wave * 2 + 1;
  const int srow0 = c0 * 16 + (lane >> 2);
  const int srow1 = c1 * 16 + (lane >> 2);
  const int scol = (lane & 3) * 8;
  const int l15 = lane & 15, kof = (lane >> 4) * 8;

  for (int k0 = 0; k0 < K; k0 += 32) {
    g2lds16(A  + (arow + srow0) * (long)K + k0 + scol, &As[c0 * 512]);
    g2lds16(A  + (arow + srow1) * (long)K + k0 + scol, &As[c1 * 512]);
    g2lds16(Bt + (bcol + srow0) * (long)K + k0 + scol, &Bs[c0 * 512]);
    g2lds16(Bt + (bcol + srow1) * (long)K + k0 + scol, &Bs[c1 * 512]);
    __syncthreads();
    bf16x8 a[4], b[4];
#pragma unroll
    for (int i = 0; i < 4; ++i)
      a[i] = *(const bf16x8*)&As[(wr * 64 + i * 16 + l15) * 32 + kof];
#pragma unroll
    for (int i = 0; i < 4; ++i)
      b[i] = *(const bf16x8*)&Bs[(wc * 64 + i * 16 + l15) * 32 + kof];
#pragma unroll
    for (int mi = 0; mi < 4; ++mi)
#pragma unroll
      for (int ni = 0; ni < 4; ++ni)
        acc[mi][ni] = __builtin_amdgcn_mfma_f32_16x16x32_bf16(
            a[mi], b[ni], acc[mi][ni], 0, 0, 0);
    __syncthreads();
  }

#pragma unroll
  for (int mi = 0; mi < 4; ++mi) {
#pragma unroll
    for (int ni = 0; ni < 4; ++ni) {
#pragma unroll
      for (int j = 0; j < 4; ++j) {
        long row = arow + wr * 64 + mi * 16 + (lane >> 4) * 4 + j;
        long col = bcol + wc * 64 + ni * 16 + l15;
        float v = acc[mi][ni][j];
        if constexpr (EPI == 0) {
          int bb = (int)(row >> 11), ss = (int)(row & 2047);
          int hh = (int)(col >> 6), dd = (int)(col & 63);
          size_t idx = (((size_t)(bb * H_ + hh)) * S_ + ss) * DK_ + dd;
          outb[idx] = (bf16)((v + bias[col]) * scale);
        } else if constexpr (EPI == 1) {
          size_t idx = (size_t)row * N + col;
          outf[idx] = v + bias[col] + resid[idx];
        } else {
          size_t idx = (size_t)row * N + col;
          float t = v + bias[col];
          outb[idx] = (bf16)(0.5f * t * (1.0f + erff(t * 0.70710678118654752f)));
        }
      }
    }
  }
}

// =====================================================================
// Flash attention, values == K (reference quirk). Q pre-scaled by 1/8.
// Q,K: [B,H,S,64] bf16. Output scattered to attn[M][D] bf16.
// Block: 64 q-rows, 4 waves x 16 rows. K-tile = 64 kv.
// =====================================================================
__global__ __launch_bounds__(256)
void attn_fwd(const bf16* __restrict__ Q, const bf16* __restrict__ Kk,
              const int* __restrict__ mask, bf16* __restrict__ O) {
  __shared__ __align__(16) bf16 Kl[64 * 64];   // [kv][d]
  __shared__ __align__(16) bf16 KTl[64 * 64];  // [d][kv]
  __shared__ __align__(16) bf16 Pl[4][16 * 64];

  const int tid = threadIdx.x, wave = tid >> 6, lane = tid & 63;
  const int bh = blockIdx.y, b = bh >> 4, h = bh & 15;
  const int q0 = blockIdx.x * 64;
  const int l15 = lane & 15, kof = (lane >> 4) * 8;

  const bf16* Qp = Q  + (size_t)bh * S_ * DK_;
  const bf16* Kp = Kk + (size_t)bh * S_ * DK_;

  const int qrow = q0 + wave * 16 + l15;
  const bf16x8 qf0 = *(const bf16x8*)&Qp[(size_t)qrow * 64 + kof];
  const bf16x8 qf1 = *(const bf16x8*)&Qp[(size_t)qrow * 64 + 32 + kof];

  f32x4 o[4] = {};
  float m_r[4], l_r[4];
#pragma unroll
  for (int j = 0; j < 4; ++j) { m_r[j] = -__builtin_inff(); l_r[j] = 0.f; }

  for (int k0 = 0; k0 < S_; k0 += 64) {
    // stage K-tile: row-major and transposed
#pragma unroll
    for (int i = 0; i < 2; ++i) {
      int e = (tid * 2 + i) * 8;          // element index in 64x64 tile
      int r = e >> 6, c = e & 63;
      bf16x8 v = *(const bf16x8*)&Kp[(size_t)(k0 + r) * 64 + c];
      *(bf16x8*)&Kl[e] = v;
#pragma unroll
      for (int jj = 0; jj < 8; ++jj) KTl[(c + jj) * 64 + r] = v[jj];
    }
    __syncthreads();

    // scores S = Q K^T (scale folded into Q)
    f32x4 s[4];
#pragma unroll
    for (int nt = 0; nt < 4; ++nt) {
      bf16x8 kf0 = *(const bf16x8*)&Kl[(nt * 16 + l15) * 64 + kof];
      bf16x8 kf1 = *(const bf16x8*)&Kl[(nt * 16 + l15) * 64 + 32 + kof];
      f32x4 z = {};
      z     = __builtin_amdgcn_mfma_f32_16x16x32_bf16(qf0, kf0, z, 0, 0, 0);
      s[nt] = __builtin_amdgcn_mfma_f32_16x16x32_bf16(qf1, kf1, z, 0, 0, 0);
    }
    // mask (reference: where(mask==0, -1e9, s))
#pragma unroll
    for (int nt = 0; nt < 4; ++nt) {
      int mv = mask[b * S_ + k0 + nt * 16 + l15];
      if (mv == 0) {
#pragma unroll
        for (int j = 0; j < 4; ++j) s[nt][j] = -1e9f;
      }
    }
    // online softmax: rows live across 16 lanes (same lane>>4 group)
    float rmax[4], rsum[4], sf[4];
#pragma unroll
    for (int j = 0; j < 4; ++j)
      rmax[j] = fmaxf(fmaxf(s[0][j], s[1][j]), fmaxf(s[2][j], s[3][j]));
#pragma unroll
    for (int d = 1; d < 16; d <<= 1)
#pragma unroll
      for (int j = 0; j < 4; ++j)
        rmax[j] = fmaxf(rmax[j], __shfl_xor(rmax[j], d));
#pragma unroll
    for (int j = 0; j < 4; ++j) {
      float mnew = fmaxf(m_r[j], rmax[j]);
      sf[j] = expf(m_r[j] - mnew);
      m_r[j] = mnew;
      rsum[j] = 0.f;
    }
#pragma unroll
    for (int nt = 0; nt < 4; ++nt)
#pragma unroll
      for (int j = 0; j < 4; ++j) {
        float p = expf(s[nt][j] - m_r[j]);
        s[nt][j] = p;
        rsum[j] += p;
      }
#pragma unroll
    for (int d = 1; d < 16; d <<= 1)
#pragma unroll
      for (int j = 0; j < 4; ++j) rsum[j] += __shfl_xor(rsum[j], d);
#pragma unroll
    for (int j = 0; j < 4; ++j) l_r[j] = l_r[j] * sf[j] + rsum[j];
#pragma unroll
    for (int nf = 0; nf < 4; ++nf)
#pragma unroll
      for (int j = 0; j < 4; ++j) o[nf][j] *= sf[j];

    // P -> LDS (per-wave region), relayout into A-operand order
#pragma unroll
    for (int nt = 0; nt < 4; ++nt)
#pragma unroll
      for (int j = 0; j < 4; ++j)
        Pl[wave][((lane >> 4) * 4 + j) * 64 + nt * 16 + l15] = (bf16)s[nt][j];

    const bf16x8 pf0 = *(const bf16x8*)&Pl[wave][l15 * 64 + kof];
    const bf16x8 pf1 = *(const bf16x8*)&Pl[wave][l15 * 64 + 32 + kof];
#pragma unroll
    for (int nf = 0; nf < 4; ++nf) {
      bf16x8 vf0 = *(const bf16x8*)&KTl[(nf * 16 + l15) * 64 + kof];
      bf16x8 vf1 = *(const bf16x8*)&KTl[(nf * 16 + l15) * 64 + 32 + kof];
      o[nf] = __builtin_amdgcn_mfma_f32_16x16x32_bf16(pf0, vf0, o[nf], 0, 0, 0);
      o[nf] = __builtin_amdgcn_mfma_f32_16x16x32_bf16(pf1, vf1, o[nf], 0, 0, 0);
    }
    __syncthreads();
  }

  // epilogue: scatter to attn buffer [M][D]
#pragma unroll
  for (int nf = 0; nf < 4; ++nf)
#pragma unroll
    for (int j = 0; j < 4; ++j) {
      int row = q0 + wave * 16 + (lane >> 4) * 4 + j;
      int col = h * 64 + nf * 16 + l15;
      O[((size_t)b * S_ + row) * D_ + col] = (bf16)(o[nf][j] / l_r[j]);
    }
}

// =====================================================================
extern "C" void kernel_launch(void* const* d_in, const int* in_sizes, int n_in,
                              void* d_out, int out_size, void* d_ws, size_t ws_size,
                              hipStream_t stream) {
  const float* x    = (const float*)d_in[0];
  const int*   mask = (const int*)d_in[1];
  const float* Wq   = (const float*)d_in[2];
  const float* bq   = (const float*)d_in[3];
  const float* Wk   = (const float*)d_in[4];
  const float* bk   = (const float*)d_in[5];
  // d_in[6]=Wv, d_in[7]=bv: dead code in the reference (value == key)
  const float* Wo   = (const float*)d_in[8];
  const float* bo   = (const float*)d_in[9];
  const float* ln1g = (const float*)d_in[10];
  const float* ln1b = (const float*)d_in[11];
  const float* W1   = (const float*)d_in[12];
  const float* b1   = (const float*)d_in[13];
  const float* W2   = (const float*)d_in[14];
  const float* b2   = (const float*)d_in[15];
  const float* ln2g = (const float*)d_in[16];
  const float* ln2b = (const float*)d_in[17];
  float* out = (float*)d_out;

  char* w = (char*)d_ws;
  auto alloc = [&](size_t bytes) {
    void* p = (void*)w;
    w += (bytes + 255) & ~(size_t)255;
    return p;
  };
  bf16* xln  = (bf16*)alloc((size_t)M_ * D_ * 2);
  bf16* WqT  = (bf16*)alloc((size_t)D_ * D_ * 2);
  bf16* WkT  = (bf16*)alloc((size_t)D_ * D_ * 2);
  bf16* WoT  = (bf16*)alloc((size_t)D_ * D_ * 2);
  bf16* W1T  = (bf16*)alloc((size_t)D_ * DFF_ * 2);
  bf16* W2T  = (bf16*)alloc((size_t)D_ * DFF_ * 2);
  bf16* Qt   = (bf16*)alloc((size_t)M_ * D_ * 2);
  bf16* Kt   = (bf16*)alloc((size_t)M_ * D_ * 2);
  bf16* attn = (bf16*)alloc((size_t)M_ * D_ * 2);
  float* x2  = (float*)alloc((size_t)M_ * D_ * 4);
  bf16* h2   = (bf16*)alloc((size_t)M_ * D_ * 2);
  bf16* act  = (bf16*)alloc((size_t)M_ * DFF_ * 2);

  dim3 blk32(32, 8);
  tcast<<<dim3(32, 32),  blk32, 0, stream>>>(Wq, WqT, D_, D_);
  tcast<<<dim3(32, 32),  blk32, 0, stream>>>(Wk, WkT, D_, D_);
  tcast<<<dim3(32, 32),  blk32, 0, stream>>>(Wo, WoT, D_, D_);
  tcast<<<dim3(128, 32), blk32, 0, stream>>>(W1, W1T, D_, DFF_);
  tcast<<<dim3(32, 128), blk32, 0, stream>>>(W2, W2T, DFF_, D_);

  ln_fwd<<<M_, 256, 0, stream>>>(x, ln1g, ln1b, xln);

  // Q (scale 1/sqrt(64) folded in) and K projections -> [B,H,S,DK]
  gemm_bt<0><<<dim3(8, 64), 256, 0, stream>>>(xln, WqT, M_, D_, D_, bq, nullptr,
                                              0.125f, nullptr, Qt);
  gemm_bt<0><<<dim3(8, 64), 256, 0, stream>>>(xln, WkT, M_, D_, D_, bk, nullptr,
                                              1.0f, nullptr, Kt);

  attn_fwd<<<dim3(S_ / 64, B_ * H_), 256, 0, stream>>>(Qt, Kt, mask, attn);

  // x2 = x + attn @ Wo + bo   (f32)
  gemm_bt<1><<<dim3(8, 64), 256, 0, stream>>>(attn, WoT, M_, D_, D_, bo, x,
                                              1.0f, x2, nullptr);

  ln_fwd<<<M_, 256, 0, stream>>>(x2, ln2g, ln2b, h2);

  // act = gelu(h2 @ W1 + b1)  (bf16)
  gemm_bt<2><<<dim3(32, 64), 256, 0, stream>>>(h2, W1T, M_, DFF_, D_, b1, nullptr,
                                               1.0f, nullptr, act);
  // out = x2 + act @ W2 + b2  (f32)
  gemm_bt<1><<<dim3(8, 64), 256, 0, stream>>>(act, W2T, M_, D_, DFF_, b2, x2,
                                              1.0f, out, nullptr);
}

// Round 2
// 682.517 us; speedup vs baseline: 1.2263x; 1.2263x over previous
//
#include <hip/hip_runtime.h>
#include <hip/hip_bf16.h>
#include <math.h>

// Problem constants (TransformerBlock: B=4,S=2048,D=1024,H=16,DFF=4096)
#define B_   4
#define S_   2048
#define D_   1024
#define H_   16
#define DK_  64
#define DFF_ 4096
#define M_   (B_*S_)   // 8192 rows

typedef __bf16 bf16;
typedef bf16 bf16x8 __attribute__((ext_vector_type(8)));
typedef bf16 bf16x4 __attribute__((ext_vector_type(4)));
typedef float f32x4 __attribute__((ext_vector_type(4)));

// ---- async global->LDS, 16B per lane, wave-uniform LDS base + lane*16 ----
__device__ __forceinline__ void g2lds16(const void* g, void* l) {
  __builtin_amdgcn_global_load_lds(
      (__attribute__((address_space(1))) void*)(void*)g,
      (__attribute__((address_space(3))) void*)l, 16, 0, 0);
}

// XOR swizzle for LDS tiles with 128-byte rows (T2 / Guideline-4 fix)
__device__ __forceinline__ void* swzp(char* base, int row, int byteofs) {
  return base + row * 128 + (byteofs ^ ((row & 7) << 4));
}

// =====================================================================
// Weight cast + transpose: W[K][N] f32 -> Wt[N][K] bf16
// =====================================================================
__global__ void tcast(const float* __restrict__ W, bf16* __restrict__ Wt,
                      int K, int N) {
  __shared__ float t[32][33];
  int n0 = blockIdx.x * 32, k0 = blockIdx.y * 32;
  int tx = threadIdx.x, ty = threadIdx.y;
#pragma unroll
  for (int i = 0; i < 4; ++i)
    t[ty + i*8][tx] = W[(size_t)(k0 + ty + i*8) * N + n0 + tx];
  __syncthreads();
#pragma unroll
  for (int i = 0; i < 4; ++i)
    Wt[(size_t)(n0 + ty + i*8) * K + k0 + tx] = (bf16)t[tx][ty + i*8];
}

// =====================================================================
// K transpose (per head): Kt[B,H,S,64] bf16 -> KT[B,H,64,S] bf16
// One block per 64x64 tile. Removes the in-attention scatter transpose.
// =====================================================================
__global__ __launch_bounds__(256)
void ktrans(const bf16* __restrict__ Kt, bf16* __restrict__ KT) {
  __shared__ bf16 t[64][72];  // +8 pad breaks bank alignment
  const int bh = blockIdx.y, s0 = blockIdx.x * 64, tid = threadIdx.x;
  const bf16* src = Kt + (size_t)bh * S_ * DK_;
  bf16* dst = KT + (size_t)bh * DK_ * S_;
#pragma unroll
  for (int i = 0; i < 2; ++i) {
    int c = tid * 2 + i;           // 512 chunks of 8 elems
    int r = c >> 3, col = (c & 7) * 8;
    *(bf16x8*)&t[r][col] = *(const bf16x8*)&src[(size_t)(s0 + r) * 64 + col];
  }
  __syncthreads();
  const int d = tid >> 2, sc = (tid & 3) * 16;
  bf16x8 v0, v1;
#pragma unroll
  for (int j = 0; j < 8; ++j) { v0[j] = t[sc + j][d]; v1[j] = t[sc + 8 + j][d]; }
  *(bf16x8*)&dst[(size_t)d * S_ + s0 + sc] = v0;
  *(bf16x8*)&dst[(size_t)d * S_ + s0 + sc + 8] = v1;
}

// =====================================================================
// LayerNorm over D=1024, one block (256 thr) per row, bf16 output
// =====================================================================
__global__ __launch_bounds__(256)
void ln_fwd(const float* __restrict__ x, const float* __restrict__ g,
            const float* __restrict__ be, bf16* __restrict__ out) {
  int row = blockIdx.x, tid = threadIdx.x;
  const float4 v = *(const float4*)&x[(size_t)row * D_ + tid * 4];
  float s = v.x + v.y + v.z + v.w;
  float q = v.x*v.x + v.y*v.y + v.z*v.z + v.w*v.w;
#pragma unroll
  for (int d = 32; d; d >>= 1) { s += __shfl_down(s, d); q += __shfl_down(q, d); }
  __shared__ float red[8];
  int wave = tid >> 6, lane = tid & 63;
  if (lane == 0) { red[wave*2] = s; red[wave*2+1] = q; }
  __syncthreads();
  float ts = red[0] + red[2] + red[4] + red[6];
  float tq = red[1] + red[3] + red[5] + red[7];
  float mean = ts * (1.0f / D_);
  float var  = tq * (1.0f / D_) - mean * mean;
  float rstd = rsqrtf(var + 1e-5f);
  const float4 gg = *(const float4*)&g[tid * 4];
  const float4 bb = *(const float4*)&be[tid * 4];
  bf16x4 ov;
  ov[0] = (bf16)((v.x - mean) * rstd * gg.x + bb.x);
  ov[1] = (bf16)((v.y - mean) * rstd * gg.y + bb.y);
  ov[2] = (bf16)((v.z - mean) * rstd * gg.z + bb.z);
  ov[3] = (bf16)((v.w - mean) * rstd * gg.w + bb.w);
  *(bf16x4*)&out[(size_t)row * D_ + tid * 4] = ov;
}

// =====================================================================
// GEMM: C[M,N] = A[M,K] @ Bt[N,K]^T  (both bf16 row-major, f32 acc)
// 128x128 tile, BK=32, 4 waves (2x2), 16x16x32 MFMA, global_load_lds.
// XCD-aware bijective blockIdx swizzle (T1; nwg % 8 == 0 on all launches).
// EPI 0: outb[B,H,S,DK] = (C + bias) * scale   (Q/K projection scatter)
// EPI 1: outf[row*N+col] = C + bias + resid    (residual add, f32 out)
// EPI 2: outb[row*N+col] = gelu_exact(C+bias)  (bf16 out)
// =====================================================================
template <int EPI>
__global__ __launch_bounds__(256)
void gemm_bt(const bf16* __restrict__ A, const bf16* __restrict__ Bt,
             int M, int N, int K,
             const float* __restrict__ bias, const float* __restrict__ resid,
             float scale, float* __restrict__ outf, bf16* __restrict__ outb) {
  __shared__ __align__(16) bf16 As[128 * 32];
  __shared__ __align__(16) bf16 Bs[128 * 32];
  const int tid = threadIdx.x;
  const int wave = tid >> 6, lane = tid & 63;
  const int wr = wave >> 1, wc = wave & 1;

  const int gx = gridDim.x, nwg = gx * gridDim.y;
  int wg = blockIdx.y * gx + blockIdx.x;
  wg = (wg & 7) * (nwg >> 3) + (wg >> 3);      // XCD chunking (bijective)
  const long arow = (long)(wg / gx) * 128;
  const long bcol = (long)(wg % gx) * 128;

  f32x4 acc[4][4] = {};

  const int c0 = wave * 2, c1 = wave * 2 + 1;
  const int srow0 = c0 * 16 + (lane >> 2);
  const int srow1 = c1 * 16 + (lane >> 2);
  const int scol = (lane & 3) * 8;
  const int l15 = lane & 15, kof = (lane >> 4) * 8;

  for (int k0 = 0; k0 < K; k0 += 32) {
    g2lds16(A  + (arow + srow0) * (long)K + k0 + scol, &As[c0 * 512]);
    g2lds16(A  + (arow + srow1) * (long)K + k0 + scol, &As[c1 * 512]);
    g2lds16(Bt + (bcol + srow0) * (long)K + k0 + scol, &Bs[c0 * 512]);
    g2lds16(Bt + (bcol + srow1) * (long)K + k0 + scol, &Bs[c1 * 512]);
    __syncthreads();
    bf16x8 a[4], b[4];
#pragma unroll
    for (int i = 0; i < 4; ++i)
      a[i] = *(const bf16x8*)&As[(wr * 64 + i * 16 + l15) * 32 + kof];
#pragma unroll
    for (int i = 0; i < 4; ++i)
      b[i] = *(const bf16x8*)&Bs[(wc * 64 + i * 16 + l15) * 32 + kof];
#pragma unroll
    for (int mi = 0; mi < 4; ++mi)
#pragma unroll
      for (int ni = 0; ni < 4; ++ni)
        acc[mi][ni] = __builtin_amdgcn_mfma_f32_16x16x32_bf16(
            a[mi], b[ni], acc[mi][ni], 0, 0, 0);
    __syncthreads();
  }

#pragma unroll
  for (int mi = 0; mi < 4; ++mi) {
#pragma unroll
    for (int ni = 0; ni < 4; ++ni) {
#pragma unroll
      for (int j = 0; j < 4; ++j) {
        long row = arow + wr * 64 + mi * 16 + (lane >> 4) * 4 + j;
        long col = bcol + wc * 64 + ni * 16 + l15;
        float v = acc[mi][ni][j];
        if constexpr (EPI == 0) {
          int bb = (int)(row >> 11), ss = (int)(row & 2047);
          int hh = (int)(col >> 6), dd = (int)(col & 63);
          size_t idx = (((size_t)(bb * H_ + hh)) * S_ + ss) * DK_ + dd;
          outb[idx] = (bf16)((v + bias[col]) * scale);
        } else if constexpr (EPI == 1) {
          size_t idx = (size_t)row * N + col;
          outf[idx] = v + bias[col] + resid[idx];
        } else {
          size_t idx = (size_t)row * N + col;
          float t = v + bias[col];
          outb[idx] = (bf16)(0.5f * t * (1.0f + erff(t * 0.70710678118654752f)));
        }
      }
    }
  }
}

// =====================================================================
// Flash attention, values == K (reference quirk).
// Q pre-scaled by (1/8)*log2(e): softmax runs in exp2 domain (exact).
// Q,Kt: [B,H,S,64] bf16; KT: [B,H,64,S] bf16 (pre-transposed).
// Block: 64 q-rows, 4 waves x 16 rows. K-tile = 64 kv.
// All LDS tiles have 128B rows -> XOR-swizzled (T2).
// =====================================================================
__global__ __launch_bounds__(256)
void attn_fwd(const bf16* __restrict__ Q, const bf16* __restrict__ Kk,
              const bf16* __restrict__ KT, const int* __restrict__ mask,
              bf16* __restrict__ O) {
  __shared__ __align__(16) char Kl[64 * 128];     // swizzled [kv][d]
  __shared__ __align__(16) char Vl[64 * 128];     // swizzled [d][kv]
  __shared__ __align__(16) char Pl[4][16 * 128];  // swizzled per-wave P

  const int tid = threadIdx.x, wave = tid >> 6, lane = tid & 63;
  const int bh = blockIdx.y, b = bh >> 4, h = bh & 15;
  const int q0 = blockIdx.x * 64;
  const int l15 = lane & 15, q4 = lane >> 4;

  const bf16* Qp = Q  + (size_t)bh * S_ * DK_;
  const bf16* Kp = Kk + (size_t)bh * S_ * DK_;
  const bf16* Tp = KT + (size_t)bh * DK_ * S_;

  const int qrow = q0 + wave * 16 + l15;
  const bf16x8 qf0 = *(const bf16x8*)&Qp[(size_t)qrow * 64 + q4 * 8];
  const bf16x8 qf1 = *(const bf16x8*)&Qp[(size_t)qrow * 64 + 32 + q4 * 8];

  // staging coords: 512 chunks of 16B over 2 tiles; 2 chunks/thread/tile
  const int c0 = tid * 2, c1 = tid * 2 + 1;
  const int sr0 = c0 >> 3, sb0 = c0 & 7;
  const int sr1 = c1 >> 3, sb1 = c1 & 7;

  f32x4 o[4] = {};
  float m_r[4], l_r[4];
#pragma unroll
  for (int j = 0; j < 4; ++j) { m_r[j] = -__builtin_inff(); l_r[j] = 0.f; }

  for (int k0 = 0; k0 < S_; k0 += 64) {
    // stage K row-major + KT (values-transposed) tiles, swizzled
    bf16x8 a0 = *(const bf16x8*)&Kp[(size_t)(k0 + sr0) * 64 + sb0 * 8];
    bf16x8 a1 = *(const bf16x8*)&Kp[(size_t)(k0 + sr1) * 64 + sb1 * 8];
    bf16x8 t0 = *(const bf16x8*)&Tp[(size_t)sr0 * S_ + k0 + sb0 * 8];
    bf16x8 t1 = *(const bf16x8*)&Tp[(size_t)sr1 * S_ + k0 + sb1 * 8];
    *(bf16x8*)swzp(Kl, sr0, sb0 * 16) = a0;
    *(bf16x8*)swzp(Kl, sr1, sb1 * 16) = a1;
    *(bf16x8*)swzp(Vl, sr0, sb0 * 16) = t0;
    *(bf16x8*)swzp(Vl, sr1, sb1 * 16) = t1;
    __syncthreads();

    // scores S' = (Q*log2e/8) K^T
    f32x4 s[4];
#pragma unroll
    for (int nt = 0; nt < 4; ++nt) {
      bf16x8 kf0 = *(const bf16x8*)swzp(Kl, nt * 16 + l15, q4 * 16);
      bf16x8 kf1 = *(const bf16x8*)swzp(Kl, nt * 16 + l15, 64 + q4 * 16);
      f32x4 z = {};
      z     = __builtin_amdgcn_mfma_f32_16x16x32_bf16(qf0, kf0, z, 0, 0, 0);
      s[nt] = __builtin_amdgcn_mfma_f32_16x16x32_bf16(qf1, kf1, z, 0, 0, 0);
    }
    // mask (reference: where(mask==0, -1e9, s))
#pragma unroll
    for (int nt = 0; nt < 4; ++nt) {
      int mv = mask[b * S_ + k0 + nt * 16 + l15];
      if (mv == 0) {
#pragma unroll
        for (int j = 0; j < 4; ++j) s[nt][j] = -1e9f;
      }
    }
    // online softmax in exp2 domain; rows live across 16 lanes
    float rmax[4], rsum[4], sf[4];
#pragma unroll
    for (int j = 0; j < 4; ++j)
      rmax[j] = fmaxf(fmaxf(s[0][j], s[1][j]), fmaxf(s[2][j], s[3][j]));
#pragma unroll
    for (int d = 1; d < 16; d <<= 1)
#pragma unroll
      for (int j = 0; j < 4; ++j)
        rmax[j] = fmaxf(rmax[j], __shfl_xor(rmax[j], d));
#pragma unroll
    for (int j = 0; j < 4; ++j) {
      float mnew = fmaxf(m_r[j], rmax[j]);
      sf[j] = __builtin_amdgcn_exp2f(m_r[j] - mnew);
      m_r[j] = mnew;
      rsum[j] = 0.f;
    }
#pragma unroll
    for (int nt = 0; nt < 4; ++nt)
#pragma unroll
      for (int j = 0; j < 4; ++j) {
        float p = __builtin_amdgcn_exp2f(s[nt][j] - m_r[j]);
        s[nt][j] = p;
        rsum[j] += p;
      }
#pragma unroll
    for (int d = 1; d < 16; d <<= 1)
#pragma unroll
      for (int j = 0; j < 4; ++j) rsum[j] += __shfl_xor(rsum[j], d);
#pragma unroll
    for (int j = 0; j < 4; ++j) l_r[j] = l_r[j] * sf[j] + rsum[j];
#pragma unroll
    for (int nf = 0; nf < 4; ++nf)
#pragma unroll
      for (int j = 0; j < 4; ++j) o[nf][j] *= sf[j];

    // P -> LDS (per-wave region, swizzled), relayout into A-operand order
#pragma unroll
    for (int nt = 0; nt < 4; ++nt)
#pragma unroll
      for (int j = 0; j < 4; ++j)
        *(bf16*)swzp(Pl[wave], q4 * 4 + j, (nt * 16 + l15) * 2) =
            (bf16)s[nt][j];

    const bf16x8 pf0 = *(const bf16x8*)swzp(Pl[wave], l15, q4 * 16);
    const bf16x8 pf1 = *(const bf16x8*)swzp(Pl[wave], l15, 64 + q4 * 16);
#pragma unroll
    for (int nf = 0; nf < 4; ++nf) {
      bf16x8 vf0 = *(const bf16x8*)swzp(Vl, nf * 16 + l15, q4 * 16);
      bf16x8 vf1 = *(const bf16x8*)swzp(Vl, nf * 16 + l15, 64 + q4 * 16);
      o[nf] = __builtin_amdgcn_mfma_f32_16x16x32_bf16(pf0, vf0, o[nf], 0, 0, 0);
      o[nf] = __builtin_amdgcn_mfma_f32_16x16x32_bf16(pf1, vf1, o[nf], 0, 0, 0);
    }
    __syncthreads();
  }

  // epilogue: scatter to attn buffer [M][D]
#pragma unroll
  for (int nf = 0; nf < 4; ++nf)
#pragma unroll
    for (int j = 0; j < 4; ++j) {
      int row = q0 + wave * 16 + q4 * 4 + j;
      int col = h * 64 + nf * 16 + l15;
      O[((size_t)b * S_ + row) * D_ + col] = (bf16)(o[nf][j] / l_r[j]);
    }
}

// =====================================================================
extern "C" void kernel_launch(void* const* d_in, const int* in_sizes, int n_in,
                              void* d_out, int out_size, void* d_ws, size_t ws_size,
                              hipStream_t stream) {
  const float* x    = (const float*)d_in[0];
  const int*   mask = (const int*)d_in[1];
  const float* Wq   = (const float*)d_in[2];
  const float* bq   = (const float*)d_in[3];
  const float* Wk   = (const float*)d_in[4];
  const float* bk   = (const float*)d_in[5];
  // d_in[6]=Wv, d_in[7]=bv: dead code in the reference (value == key)
  const float* Wo   = (const float*)d_in[8];
  const float* bo   = (const float*)d_in[9];
  const float* ln1g = (const float*)d_in[10];
  const float* ln1b = (const float*)d_in[11];
  const float* W1   = (const float*)d_in[12];
  const float* b1   = (const float*)d_in[13];
  const float* W2   = (const float*)d_in[14];
  const float* b2   = (const float*)d_in[15];
  const float* ln2g = (const float*)d_in[16];
  const float* ln2b = (const float*)d_in[17];
  float* out = (float*)d_out;

  char* w = (char*)d_ws;
  auto alloc = [&](size_t bytes) {
    void* p = (void*)w;
    w += (bytes + 255) & ~(size_t)255;
    return p;
  };
  bf16* xln  = (bf16*)alloc((size_t)M_ * D_ * 2);
  bf16* WqT  = (bf16*)alloc((size_t)D_ * D_ * 2);
  bf16* WkT  = (bf16*)alloc((size_t)D_ * D_ * 2);
  bf16* WoT  = (bf16*)alloc((size_t)D_ * D_ * 2);
  bf16* W1T  = (bf16*)alloc((size_t)D_ * DFF_ * 2);
  bf16* W2T  = (bf16*)alloc((size_t)D_ * DFF_ * 2);
  bf16* Qt   = (bf16*)alloc((size_t)M_ * D_ * 2);
  bf16* Kt   = (bf16*)alloc((size_t)M_ * D_ * 2);
  bf16* KTt  = (bf16*)alloc((size_t)M_ * D_ * 2);
  bf16* attn = (bf16*)alloc((size_t)M_ * D_ * 2);
  float* x2  = (float*)alloc((size_t)M_ * D_ * 4);
  bf16* h2   = (bf16*)alloc((size_t)M_ * D_ * 2);
  bf16* act  = (bf16*)alloc((size_t)M_ * DFF_ * 2);

  dim3 blk32(32, 8);
  tcast<<<dim3(32, 32),  blk32, 0, stream>>>(Wq, WqT, D_, D_);
  tcast<<<dim3(32, 32),  blk32, 0, stream>>>(Wk, WkT, D_, D_);
  tcast<<<dim3(32, 32),  blk32, 0, stream>>>(Wo, WoT, D_, D_);
  tcast<<<dim3(128, 32), blk32, 0, stream>>>(W1, W1T, D_, DFF_);
  tcast<<<dim3(32, 128), blk32, 0, stream>>>(W2, W2T, DFF_, D_);

  ln_fwd<<<M_, 256, 0, stream>>>(x, ln1g, ln1b, xln);

  // Q (scale (1/8)*log2e folded in -> softmax in exp2 domain) and K proj
  gemm_bt<0><<<dim3(8, 64), 256, 0, stream>>>(xln, WqT, M_, D_, D_, bq, nullptr,
                                              0.125f * 1.4426950408889634f,
                                              nullptr, Qt);
  gemm_bt<0><<<dim3(8, 64), 256, 0, stream>>>(xln, WkT, M_, D_, D_, bk, nullptr,
                                              1.0f, nullptr, Kt);

  ktrans<<<dim3(S_ / 64, B_ * H_), 256, 0, stream>>>(Kt, KTt);

  attn_fwd<<<dim3(S_ / 64, B_ * H_), 256, 0, stream>>>(Qt, Kt, KTt, mask, attn);

  // x2 = x + attn @ Wo + bo   (f32)
  gemm_bt<1><<<dim3(8, 64), 256, 0, stream>>>(attn, WoT, M_, D_, D_, bo, x,
                                              1.0f, x2, nullptr);

  ln_fwd<<<M_, 256, 0, stream>>>(x2, ln2g, ln2b, h2);

  // act = gelu(h2 @ W1 + b1)  (bf16)
  gemm_bt<2><<<dim3(32, 64), 256, 0, stream>>>(h2, W1T, M_, DFF_, D_, b1, nullptr,
                                               1.0f, nullptr, act);
  // out = x2 + act @ W2 + b2  (f32)
  gemm_bt<1><<<dim3(8, 64), 256, 0, stream>>>(act, W2T, M_, D_, DFF_, b2, x2,
                                              1.0f, out, nullptr);
}

// Round 3
// 661.484 us; speedup vs baseline: 1.2653x; 1.0318x over previous
//
#include <hip/hip_runtime.h>
#include <hip/hip_bf16.h>
#include <math.h>

// Problem constants (TransformerBlock: B=4,S=2048,D=1024,H=16,DFF=4096)
#define B_   4
#define S_   2048
#define D_   1024
#define H_   16
#define DK_  64
#define DFF_ 4096
#define M_   (B_*S_)   // 8192 rows

typedef __bf16 bf16;
typedef bf16 bf16x8 __attribute__((ext_vector_type(8)));
typedef bf16 bf16x4 __attribute__((ext_vector_type(4)));
typedef float f32x4 __attribute__((ext_vector_type(4)));

// ---- async global->LDS, 16B per lane, wave-uniform LDS base + lane*16 ----
__device__ __forceinline__ void g2lds16(const void* g, void* l) {
  __builtin_amdgcn_global_load_lds(
      (__attribute__((address_space(1))) void*)(void*)g,
      (__attribute__((address_space(3))) void*)l, 16, 0, 0);
}

// XOR swizzle for LDS tiles with 128-byte rows (T2 / Guideline-4 fix)
__device__ __forceinline__ void* swzp(char* base, int row, int byteofs) {
  return base + row * 128 + (byteofs ^ ((row & 7) << 4));
}

// =====================================================================
// All weight casts+transposes in ONE kernel (W[K][N] f32 -> Wt[N][K] bf16)
// Region map over flat blockIdx.x (11264 blocks total):
//   [0,1024)    Wq  -> WqkT rows 0..1023      (1024x1024)
//   [1024,2048) Wk  -> WqkT rows 1024..2047   (1024x1024)
//   [2048,3072) Wo  -> WoT                    (1024x1024)
//   [3072,7168) W1  -> W1T                    (K=1024,N=4096)
//   [7168,11264)W2  -> W2T                    (K=4096,N=1024)
// =====================================================================
__global__ void tcast_all(const float* __restrict__ Wq, const float* __restrict__ Wk,
                          const float* __restrict__ Wo, const float* __restrict__ W1,
                          const float* __restrict__ W2,
                          bf16* __restrict__ WqkT, bf16* __restrict__ WoT,
                          bf16* __restrict__ W1T, bf16* __restrict__ W2T) {
  __shared__ float t[32][33];
  int bid = blockIdx.x;
  const float* src; bf16* dst; int K, N, bx, by;
  if (bid < 1024)      { src = Wq; dst = WqkT;            K = 1024; N = 1024; bx = bid & 31;  by = bid >> 5; }
  else if (bid < 2048) { bid -= 1024; src = Wk; dst = WqkT + 1024 * 1024; K = 1024; N = 1024; bx = bid & 31;  by = bid >> 5; }
  else if (bid < 3072) { bid -= 2048; src = Wo; dst = WoT; K = 1024; N = 1024; bx = bid & 31;  by = bid >> 5; }
  else if (bid < 7168) { bid -= 3072; src = W1; dst = W1T; K = 1024; N = 4096; bx = bid & 127; by = bid >> 7; }
  else                 { bid -= 7168; src = W2; dst = W2T; K = 4096; N = 1024; bx = bid & 31;  by = bid >> 5; }
  int n0 = bx * 32, k0 = by * 32;
  int tx = threadIdx.x, ty = threadIdx.y;
#pragma unroll
  for (int i = 0; i < 4; ++i)
    t[ty + i*8][tx] = src[(size_t)(k0 + ty + i*8) * N + n0 + tx];
  __syncthreads();
#pragma unroll
  for (int i = 0; i < 4; ++i)
    dst[(size_t)(n0 + ty + i*8) * K + k0 + tx] = (bf16)t[tx][ty + i*8];
}

// =====================================================================
// K transpose (per head): Kt[B,H,S,64] bf16 -> KT[B,H,64,S] bf16
// =====================================================================
__global__ __launch_bounds__(256)
void ktrans(const bf16* __restrict__ Kt, bf16* __restrict__ KT) {
  __shared__ bf16 t[64][72];
  const int bh = blockIdx.y, s0 = blockIdx.x * 64, tid = threadIdx.x;
  const bf16* src = Kt + (size_t)bh * S_ * DK_;
  bf16* dst = KT + (size_t)bh * DK_ * S_;
#pragma unroll
  for (int i = 0; i < 2; ++i) {
    int c = tid * 2 + i;
    int r = c >> 3, col = (c & 7) * 8;
    *(bf16x8*)&t[r][col] = *(const bf16x8*)&src[(size_t)(s0 + r) * 64 + col];
  }
  __syncthreads();
  const int d = tid >> 2, sc = (tid & 3) * 16;
  bf16x8 v0, v1;
#pragma unroll
  for (int j = 0; j < 8; ++j) { v0[j] = t[sc + j][d]; v1[j] = t[sc + 8 + j][d]; }
  *(bf16x8*)&dst[(size_t)d * S_ + s0 + sc] = v0;
  *(bf16x8*)&dst[(size_t)d * S_ + s0 + sc + 8] = v1;
}

// =====================================================================
// LayerNorm over D=1024, one block (256 thr) per row, bf16 output
// =====================================================================
__global__ __launch_bounds__(256)
void ln_fwd(const float* __restrict__ x, const float* __restrict__ g,
            const float* __restrict__ be, bf16* __restrict__ out) {
  int row = blockIdx.x, tid = threadIdx.x;
  const float4 v = *(const float4*)&x[(size_t)row * D_ + tid * 4];
  float s = v.x + v.y + v.z + v.w;
  float q = v.x*v.x + v.y*v.y + v.z*v.z + v.w*v.w;
#pragma unroll
  for (int d = 32; d; d >>= 1) { s += __shfl_down(s, d); q += __shfl_down(q, d); }
  __shared__ float red[8];
  int wave = tid >> 6, lane = tid & 63;
  if (lane == 0) { red[wave*2] = s; red[wave*2+1] = q; }
  __syncthreads();
  float ts = red[0] + red[2] + red[4] + red[6];
  float tq = red[1] + red[3] + red[5] + red[7];
  float mean = ts * (1.0f / D_);
  float var  = tq * (1.0f / D_) - mean * mean;
  float rstd = rsqrtf(var + 1e-5f);
  const float4 gg = *(const float4*)&g[tid * 4];
  const float4 bb = *(const float4*)&be[tid * 4];
  bf16x4 ov;
  ov[0] = (bf16)((v.x - mean) * rstd * gg.x + bb.x);
  ov[1] = (bf16)((v.y - mean) * rstd * gg.y + bb.y);
  ov[2] = (bf16)((v.z - mean) * rstd * gg.z + bb.z);
  ov[3] = (bf16)((v.w - mean) * rstd * gg.w + bb.w);
  *(bf16x4*)&out[(size_t)row * D_ + tid * 4] = ov;
}

// =====================================================================
// GEMM: C[M,N] = A[M,K] @ Bt[N,K]^T  (both bf16 row-major, f32 acc)
// 128x128 tile, BK=32, 4 waves (2x2), 16x16x32 MFMA, global_load_lds.
// XCD-aware bijective blockIdx swizzle (T1; nwg % 8 == 0 on all launches).
// EPI 0: fused Q/K projection scatter: col<1024 -> Q (scaled), else K.
// EPI 1: outf[row*N+col] = C + bias + resid    (residual add, f32 out)
// EPI 2: outb[row*N+col] = gelu_exact(C+bias)  (bf16 out)
// =====================================================================
template <int EPI>
__global__ __launch_bounds__(256)
void gemm_bt(const bf16* __restrict__ A, const bf16* __restrict__ Bt,
             int M, int N, int K,
             const float* __restrict__ bias, const float* __restrict__ bias2,
             const float* __restrict__ resid, float scale,
             float* __restrict__ outf, bf16* __restrict__ outb,
             bf16* __restrict__ outb2) {
  __shared__ __align__(16) bf16 As[128 * 32];
  __shared__ __align__(16) bf16 Bs[128 * 32];
  const int tid = threadIdx.x;
  const int wave = tid >> 6, lane = tid & 63;
  const int wr = wave >> 1, wc = wave & 1;

  const int gx = gridDim.x, nwg = gx * gridDim.y;
  int wg = blockIdx.y * gx + blockIdx.x;
  wg = (wg & 7) * (nwg >> 3) + (wg >> 3);      // XCD chunking (bijective)
  const long arow = (long)(wg / gx) * 128;
  const long bcol = (long)(wg % gx) * 128;

  f32x4 acc[4][4] = {};

  const int c0 = wave * 2, c1 = wave * 2 + 1;
  const int srow0 = c0 * 16 + (lane >> 2);
  const int srow1 = c1 * 16 + (lane >> 2);
  const int scol = (lane & 3) * 8;
  const int l15 = lane & 15, kof = (lane >> 4) * 8;

  for (int k0 = 0; k0 < K; k0 += 32) {
    g2lds16(A  + (arow + srow0) * (long)K + k0 + scol, &As[c0 * 512]);
    g2lds16(A  + (arow + srow1) * (long)K + k0 + scol, &As[c1 * 512]);
    g2lds16(Bt + (bcol + srow0) * (long)K + k0 + scol, &Bs[c0 * 512]);
    g2lds16(Bt + (bcol + srow1) * (long)K + k0 + scol, &Bs[c1 * 512]);
    __syncthreads();
    bf16x8 a[4], b[4];
#pragma unroll
    for (int i = 0; i < 4; ++i)
      a[i] = *(const bf16x8*)&As[(wr * 64 + i * 16 + l15) * 32 + kof];
#pragma unroll
    for (int i = 0; i < 4; ++i)
      b[i] = *(const bf16x8*)&Bs[(wc * 64 + i * 16 + l15) * 32 + kof];
#pragma unroll
    for (int mi = 0; mi < 4; ++mi)
#pragma unroll
      for (int ni = 0; ni < 4; ++ni)
        acc[mi][ni] = __builtin_amdgcn_mfma_f32_16x16x32_bf16(
            a[mi], b[ni], acc[mi][ni], 0, 0, 0);
    __syncthreads();
  }

#pragma unroll
  for (int mi = 0; mi < 4; ++mi) {
#pragma unroll
    for (int ni = 0; ni < 4; ++ni) {
#pragma unroll
      for (int j = 0; j < 4; ++j) {
        long row = arow + wr * 64 + mi * 16 + (lane >> 4) * 4 + j;
        long col = bcol + wc * 64 + ni * 16 + l15;
        float v = acc[mi][ni][j];
        if constexpr (EPI == 0) {
          int bb = (int)(row >> 11), ss = (int)(row & 2047);
          int hh = (int)(col >> 6) & 15, dd = (int)(col & 63);
          size_t idx = (((size_t)(bb * H_ + hh)) * S_ + ss) * DK_ + dd;
          if (col < 1024) outb[idx]  = (bf16)((v + bias[col]) * scale);
          else            outb2[idx] = (bf16)(v + bias2[col - 1024]);
        } else if constexpr (EPI == 1) {
          size_t idx = (size_t)row * N + col;
          outf[idx] = v + bias[col] + resid[idx];
        } else {
          size_t idx = (size_t)row * N + col;
          float t = v + bias[col];
          outb[idx] = (bf16)(0.5f * t * (1.0f + erff(t * 0.70710678118654752f)));
        }
      }
    }
  }
}

// =====================================================================
// Flash attention, values == K (reference quirk).
// Q pre-scaled by (1/8)*log2(e): softmax runs in exp2 domain (exact).
// Q,Kt: [B,H,S,64] bf16; KT: [B,H,64,S] bf16 (pre-transposed).
// Block: 64 q-rows, 4 waves x 16 rows. K-tile = 64 kv. XOR-swizzled LDS.
// This round: T13 defer-max (THR=8 in log2 units), row-sum via ones-MFMA
// (no sum shuffles), T14 async-stage split, mask ballot fast-path.
// =====================================================================
__global__ __launch_bounds__(256)
void attn_fwd(const bf16* __restrict__ Q, const bf16* __restrict__ Kk,
              const bf16* __restrict__ KT, const int* __restrict__ mask,
              bf16* __restrict__ O) {
  __shared__ __align__(16) char Kl[64 * 128];     // swizzled [kv][d]
  __shared__ __align__(16) char Vl[64 * 128];     // swizzled [d][kv]
  __shared__ __align__(16) char Pl[4][16 * 128];  // swizzled per-wave P

  const int tid = threadIdx.x, wave = tid >> 6, lane = tid & 63;
  const int bh = blockIdx.y, b = bh >> 4, h = bh & 15;
  const int q0 = blockIdx.x * 64;
  const int l15 = lane & 15, q4 = lane >> 4;

  const bf16* Qp = Q  + (size_t)bh * S_ * DK_;
  const bf16* Kp = Kk + (size_t)bh * S_ * DK_;
  const bf16* Tp = KT + (size_t)bh * DK_ * S_;

  const int qrow = q0 + wave * 16 + l15;
  const bf16x8 qf0 = *(const bf16x8*)&Qp[(size_t)qrow * 64 + q4 * 8];
  const bf16x8 qf1 = *(const bf16x8*)&Qp[(size_t)qrow * 64 + 32 + q4 * 8];

  // staging coords: 512 chunks of 16B over 2 tiles; 2 chunks/thread/tile
  const int c0 = tid * 2, c1 = tid * 2 + 1;
  const int sr0 = c0 >> 3, sb0 = c0 & 7;
  const int sr1 = c1 >> 3, sb1 = c1 & 7;

  // hoisted swizzled P-store byte offsets (loop-invariant)
  int poff[16];
#pragma unroll
  for (int nt = 0; nt < 4; ++nt)
#pragma unroll
    for (int j = 0; j < 4; ++j) {
      int r = q4 * 4 + j;
      poff[nt * 4 + j] = r * 128 + ((((nt * 16 + l15) * 2)) ^ ((r & 7) << 4));
    }

  bf16x8 onesv;
#pragma unroll
  for (int i = 0; i < 8; ++i) onesv[i] = (bf16)1.0f;

  f32x4 o[4] = {};
  f32x4 ol = {};           // running row-sum (replicated across cols)
  float m_r[4];
#pragma unroll
  for (int j = 0; j < 4; ++j) m_r[j] = -__builtin_inff();

  // T14 prologue: preload tile 0 into regs
  bf16x8 a0 = *(const bf16x8*)&Kp[(size_t)sr0 * 64 + sb0 * 8];
  bf16x8 a1 = *(const bf16x8*)&Kp[(size_t)sr1 * 64 + sb1 * 8];
  bf16x8 t0 = *(const bf16x8*)&Tp[(size_t)sr0 * S_ + sb0 * 8];
  bf16x8 t1 = *(const bf16x8*)&Tp[(size_t)sr1 * S_ + sb1 * 8];

  for (int k0 = 0; k0 < S_; k0 += 64) {
    // write staged regs to LDS (swizzled)
    *(bf16x8*)swzp(Kl, sr0, sb0 * 16) = a0;
    *(bf16x8*)swzp(Kl, sr1, sb1 * 16) = a1;
    *(bf16x8*)swzp(Vl, sr0, sb0 * 16) = t0;
    *(bf16x8*)swzp(Vl, sr1, sb1 * 16) = t1;
    __syncthreads();

    // T14: issue next tile's global loads now; consumed next iteration
    const int nk = k0 + 64;
    if (nk < S_) {
      a0 = *(const bf16x8*)&Kp[(size_t)(nk + sr0) * 64 + sb0 * 8];
      a1 = *(const bf16x8*)&Kp[(size_t)(nk + sr1) * 64 + sb1 * 8];
      t0 = *(const bf16x8*)&Tp[(size_t)sr0 * S_ + nk + sb0 * 8];
      t1 = *(const bf16x8*)&Tp[(size_t)sr1 * S_ + nk + sb1 * 8];
    }

    // mask fast path: 64 lanes cover the 64 kv of this tile
    const int mv = mask[b * S_ + k0 + lane];
    const bool anyz = __any(mv == 0);

    // scores S' = (Q*log2e/8) K^T
    f32x4 s[4];
#pragma unroll
    for (int nt = 0; nt < 4; ++nt) {
      bf16x8 kf0 = *(const bf16x8*)swzp(Kl, nt * 16 + l15, q4 * 16);
      bf16x8 kf1 = *(const bf16x8*)swzp(Kl, nt * 16 + l15, 64 + q4 * 16);
      f32x4 z = {};
      z     = __builtin_amdgcn_mfma_f32_16x16x32_bf16(qf0, kf0, z, 0, 0, 0);
      s[nt] = __builtin_amdgcn_mfma_f32_16x16x32_bf16(qf1, kf1, z, 0, 0, 0);
    }
    if (anyz) {
#pragma unroll
      for (int nt = 0; nt < 4; ++nt) {
        int m2 = mask[b * S_ + k0 + nt * 16 + l15];
        if (m2 == 0) {
#pragma unroll
          for (int j = 0; j < 4; ++j) s[nt][j] = -1e9f;
        }
      }
    }

    // per-row tile max (16-lane butterfly)
    float tm[4];
#pragma unroll
    for (int j = 0; j < 4; ++j)
      tm[j] = fmaxf(fmaxf(s[0][j], s[1][j]), fmaxf(s[2][j], s[3][j]));
#pragma unroll
    for (int d = 1; d < 16; d <<= 1)
#pragma unroll
      for (int j = 0; j < 4; ++j)
        tm[j] = fmaxf(tm[j], __shfl_xor(tm[j], d));

    // T13 defer-max: only rescale when some row grew by > 8 (log2 units)
    bool ok = true;
#pragma unroll
    for (int j = 0; j < 4; ++j) ok = ok && (tm[j] <= m_r[j] + 8.0f);
    if (!__all(ok)) {
#pragma unroll
      for (int j = 0; j < 4; ++j) {
        float mn = fmaxf(m_r[j], tm[j]);
        float sf = __builtin_amdgcn_exp2f(m_r[j] - mn);
        m_r[j] = mn;
        ol[j] *= sf;
#pragma unroll
        for (int nf = 0; nf < 4; ++nf) o[nf][j] *= sf;
      }
    }

    // P = exp2(S' - m) -> LDS (bf16, swizzled, hoisted offsets)
#pragma unroll
    for (int nt = 0; nt < 4; ++nt)
#pragma unroll
      for (int j = 0; j < 4; ++j)
        *(bf16*)(&Pl[wave][0] + poff[nt * 4 + j]) =
            (bf16)__builtin_amdgcn_exp2f(s[nt][j] - m_r[j]);

    const bf16x8 pf0 = *(const bf16x8*)swzp(Pl[wave], l15, q4 * 16);
    const bf16x8 pf1 = *(const bf16x8*)swzp(Pl[wave], l15, 64 + q4 * 16);

    // row-sum via ones-MFMA (replaces 16 shuffle+add): bf16-consistent
    ol = __builtin_amdgcn_mfma_f32_16x16x32_bf16(pf0, onesv, ol, 0, 0, 0);
    ol = __builtin_amdgcn_mfma_f32_16x16x32_bf16(pf1, onesv, ol, 0, 0, 0);

#pragma unroll
    for (int nf = 0; nf < 4; ++nf) {
      bf16x8 vf0 = *(const bf16x8*)swzp(Vl, nf * 16 + l15, q4 * 16);
      bf16x8 vf1 = *(const bf16x8*)swzp(Vl, nf * 16 + l15, 64 + q4 * 16);
      o[nf] = __builtin_amdgcn_mfma_f32_16x16x32_bf16(pf0, vf0, o[nf], 0, 0, 0);
      o[nf] = __builtin_amdgcn_mfma_f32_16x16x32_bf16(pf1, vf1, o[nf], 0, 0, 0);
    }
    __syncthreads();
  }

  // epilogue: scatter to attn buffer [M][D]
#pragma unroll
  for (int nf = 0; nf < 4; ++nf)
#pragma unroll
    for (int j = 0; j < 4; ++j) {
      int row = q0 + wave * 16 + q4 * 4 + j;
      int col = h * 64 + nf * 16 + l15;
      O[((size_t)b * S_ + row) * D_ + col] = (bf16)(o[nf][j] / ol[j]);
    }
}

// =====================================================================
extern "C" void kernel_launch(void* const* d_in, const int* in_sizes, int n_in,
                              void* d_out, int out_size, void* d_ws, size_t ws_size,
                              hipStream_t stream) {
  const float* x    = (const float*)d_in[0];
  const int*   mask = (const int*)d_in[1];
  const float* Wq   = (const float*)d_in[2];
  const float* bq   = (const float*)d_in[3];
  const float* Wk   = (const float*)d_in[4];
  const float* bk   = (const float*)d_in[5];
  // d_in[6]=Wv, d_in[7]=bv: dead code in the reference (value == key)
  const float* Wo   = (const float*)d_in[8];
  const float* bo   = (const float*)d_in[9];
  const float* ln1g = (const float*)d_in[10];
  const float* ln1b = (const float*)d_in[11];
  const float* W1   = (const float*)d_in[12];
  const float* b1   = (const float*)d_in[13];
  const float* W2   = (const float*)d_in[14];
  const float* b2   = (const float*)d_in[15];
  const float* ln2g = (const float*)d_in[16];
  const float* ln2b = (const float*)d_in[17];
  float* out = (float*)d_out;

  char* w = (char*)d_ws;
  auto alloc = [&](size_t bytes) {
    void* p = (void*)w;
    w += (bytes + 255) & ~(size_t)255;
    return p;
  };
  bf16* xln  = (bf16*)alloc((size_t)M_ * D_ * 2);
  bf16* WqkT = (bf16*)alloc((size_t)2 * D_ * D_ * 2);
  bf16* WoT  = (bf16*)alloc((size_t)D_ * D_ * 2);
  bf16* W1T  = (bf16*)alloc((size_t)D_ * DFF_ * 2);
  bf16* W2T  = (bf16*)alloc((size_t)D_ * DFF_ * 2);
  bf16* Qt   = (bf16*)alloc((size_t)M_ * D_ * 2);
  bf16* Kt   = (bf16*)alloc((size_t)M_ * D_ * 2);
  bf16* KTt  = (bf16*)alloc((size_t)M_ * D_ * 2);
  bf16* attn = (bf16*)alloc((size_t)M_ * D_ * 2);
  float* x2  = (float*)alloc((size_t)M_ * D_ * 4);
  bf16* h2   = (bf16*)alloc((size_t)M_ * D_ * 2);
  bf16* act  = (bf16*)alloc((size_t)M_ * DFF_ * 2);

  tcast_all<<<11264, dim3(32, 8), 0, stream>>>(Wq, Wk, Wo, W1, W2,
                                               WqkT, WoT, W1T, W2T);

  ln_fwd<<<M_, 256, 0, stream>>>(x, ln1g, ln1b, xln);

  // fused Q+K projection; Q scale (1/8)*log2e folded (exp2-domain softmax)
  gemm_bt<0><<<dim3(16, 64), 256, 0, stream>>>(
      xln, WqkT, M_, 2048, 1024, bq, bk, nullptr,
      0.125f * 1.4426950408889634f, nullptr, Qt, Kt);

  ktrans<<<dim3(S_ / 64, B_ * H_), 256, 0, stream>>>(Kt, KTt);

  attn_fwd<<<dim3(S_ / 64, B_ * H_), 256, 0, stream>>>(Qt, Kt, KTt, mask, attn);

  // x2 = x + attn @ Wo + bo   (f32)
  gemm_bt<1><<<dim3(8, 64), 256, 0, stream>>>(attn, WoT, M_, 1024, 1024,
                                              bo, nullptr, x, 1.0f,
                                              x2, nullptr, nullptr);

  ln_fwd<<<M_, 256, 0, stream>>>(x2, ln2g, ln2b, h2);

  // act = gelu(h2 @ W1 + b1)  (bf16)
  gemm_bt<2><<<dim3(32, 64), 256, 0, stream>>>(h2, W1T, M_, 4096, 1024,
                                               b1, nullptr, nullptr, 1.0f,
                                               nullptr, act, nullptr);
  // out = x2 + act @ W2 + b2  (f32)
  gemm_bt<1><<<dim3(8, 64), 256, 0, stream>>>(act, W2T, M_, 1024, 4096,
                                              b2, nullptr, x2, 1.0f,
                                              out, nullptr, nullptr);
}

// Round 4
// 597.651 us; speedup vs baseline: 1.4005x; 1.1068x over previous
//
#include <hip/hip_runtime.h>
#include <hip/hip_bf16.h>
#include <math.h>

// Problem constants (TransformerBlock: B=4,S=2048,D=1024,H=16,DFF=4096)
#define B_   4
#define S_   2048
#define D_   1024
#define H_   16
#define DK_  64
#define DFF_ 4096
#define M_   (B_*S_)   // 8192 rows

typedef __bf16 bf16;
typedef bf16 bf16x8 __attribute__((ext_vector_type(8)));
typedef bf16 bf16x4 __attribute__((ext_vector_type(4)));
typedef float f32x4 __attribute__((ext_vector_type(4)));

// ---- async global->LDS, 16B per lane, wave-uniform LDS base + lane*16 ----
__device__ __forceinline__ void g2lds16(const void* g, void* l) {
  __builtin_amdgcn_global_load_lds(
      (__attribute__((address_space(1))) void*)(void*)g,
      (__attribute__((address_space(3))) void*)l, 16, 0, 0);
}

// XOR swizzle for LDS tiles with 128-byte rows (T2 / Guideline-4 fix)
__device__ __forceinline__ void* swzp(char* base, int row, int byteofs) {
  return base + row * 128 + (byteofs ^ ((row & 7) << 4));
}

// =====================================================================
// All weight casts+transposes in ONE kernel (W[K][N] f32 -> Wt[N][K] bf16)
// =====================================================================
__global__ void tcast_all(const float* __restrict__ Wq, const float* __restrict__ Wk,
                          const float* __restrict__ Wo, const float* __restrict__ W1,
                          const float* __restrict__ W2,
                          bf16* __restrict__ WqkT, bf16* __restrict__ WoT,
                          bf16* __restrict__ W1T, bf16* __restrict__ W2T) {
  __shared__ float t[32][33];
  int bid = blockIdx.x;
  const float* src; bf16* dst; int K, N, bx, by;
  if (bid < 1024)      { src = Wq; dst = WqkT;            K = 1024; N = 1024; bx = bid & 31;  by = bid >> 5; }
  else if (bid < 2048) { bid -= 1024; src = Wk; dst = WqkT + 1024 * 1024; K = 1024; N = 1024; bx = bid & 31;  by = bid >> 5; }
  else if (bid < 3072) { bid -= 2048; src = Wo; dst = WoT; K = 1024; N = 1024; bx = bid & 31;  by = bid >> 5; }
  else if (bid < 7168) { bid -= 3072; src = W1; dst = W1T; K = 1024; N = 4096; bx = bid & 127; by = bid >> 7; }
  else                 { bid -= 7168; src = W2; dst = W2T; K = 4096; N = 1024; bx = bid & 31;  by = bid >> 5; }
  int n0 = bx * 32, k0 = by * 32;
  int tx = threadIdx.x, ty = threadIdx.y;
#pragma unroll
  for (int i = 0; i < 4; ++i)
    t[ty + i*8][tx] = src[(size_t)(k0 + ty + i*8) * N + n0 + tx];
  __syncthreads();
#pragma unroll
  for (int i = 0; i < 4; ++i)
    dst[(size_t)(n0 + ty + i*8) * K + k0 + tx] = (bf16)t[tx][ty + i*8];
}

// =====================================================================
// K transpose (per head): Kt[B,H,S,64] bf16 -> KT[B,H,64,S] bf16
// =====================================================================
__global__ __launch_bounds__(256)
void ktrans(const bf16* __restrict__ Kt, bf16* __restrict__ KT) {
  __shared__ bf16 t[64][72];
  const int bh = blockIdx.y, s0 = blockIdx.x * 64, tid = threadIdx.x;
  const bf16* src = Kt + (size_t)bh * S_ * DK_;
  bf16* dst = KT + (size_t)bh * DK_ * S_;
#pragma unroll
  for (int i = 0; i < 2; ++i) {
    int c = tid * 2 + i;
    int r = c >> 3, col = (c & 7) * 8;
    *(bf16x8*)&t[r][col] = *(const bf16x8*)&src[(size_t)(s0 + r) * 64 + col];
  }
  __syncthreads();
  const int d = tid >> 2, sc = (tid & 3) * 16;
  bf16x8 v0, v1;
#pragma unroll
  for (int j = 0; j < 8; ++j) { v0[j] = t[sc + j][d]; v1[j] = t[sc + 8 + j][d]; }
  *(bf16x8*)&dst[(size_t)d * S_ + s0 + sc] = v0;
  *(bf16x8*)&dst[(size_t)d * S_ + s0 + sc + 8] = v1;
}

// =====================================================================
// LayerNorm over D=1024, one block (256 thr) per row, bf16 output
// =====================================================================
__global__ __launch_bounds__(256)
void ln_fwd(const float* __restrict__ x, const float* __restrict__ g,
            const float* __restrict__ be, bf16* __restrict__ out) {
  int row = blockIdx.x, tid = threadIdx.x;
  const float4 v = *(const float4*)&x[(size_t)row * D_ + tid * 4];
  float s = v.x + v.y + v.z + v.w;
  float q = v.x*v.x + v.y*v.y + v.z*v.z + v.w*v.w;
#pragma unroll
  for (int d = 32; d; d >>= 1) { s += __shfl_down(s, d); q += __shfl_down(q, d); }
  __shared__ float red[8];
  int wave = tid >> 6, lane = tid & 63;
  if (lane == 0) { red[wave*2] = s; red[wave*2+1] = q; }
  __syncthreads();
  float ts = red[0] + red[2] + red[4] + red[6];
  float tq = red[1] + red[3] + red[5] + red[7];
  float mean = ts * (1.0f / D_);
  float var  = tq * (1.0f / D_) - mean * mean;
  float rstd = rsqrtf(var + 1e-5f);
  const float4 gg = *(const float4*)&g[tid * 4];
  const float4 bb = *(const float4*)&be[tid * 4];
  bf16x4 ov;
  ov[0] = (bf16)((v.x - mean) * rstd * gg.x + bb.x);
  ov[1] = (bf16)((v.y - mean) * rstd * gg.y + bb.y);
  ov[2] = (bf16)((v.z - mean) * rstd * gg.z + bb.z);
  ov[3] = (bf16)((v.w - mean) * rstd * gg.w + bb.w);
  *(bf16x4*)&out[(size_t)row * D_ + tid * 4] = ov;
}

// =====================================================================
// GEMM: C[M,N] = A[M,K] @ Bt[N,K]^T  (both bf16 row-major, f32 acc)
// 128x128 tile, BK=32, 4 waves (2x2), 16x16x32 MFMA, global_load_lds.
// T3-minimum 2-phase: explicit LDS double-buffer; stage(t+1) issued
// BEFORE compute(t); ONE barrier per K-step (vmcnt(0)+lgkmcnt(0) drain
// by __syncthreads makes it race-free by construction).
// XCD-aware bijective blockIdx swizzle (T1).
// =====================================================================
template <int EPI>
__global__ __launch_bounds__(256)
void gemm_bt(const bf16* __restrict__ A, const bf16* __restrict__ Bt,
             int M, int N, int K,
             const float* __restrict__ bias, const float* __restrict__ bias2,
             const float* __restrict__ resid, float scale,
             float* __restrict__ outf, bf16* __restrict__ outb,
             bf16* __restrict__ outb2) {
  __shared__ __align__(16) bf16 As[2][128 * 32];
  __shared__ __align__(16) bf16 Bs[2][128 * 32];
  const int tid = threadIdx.x;
  const int wave = tid >> 6, lane = tid & 63;
  const int wr = wave >> 1, wc = wave & 1;

  const int gx = gridDim.x, nwg = gx * gridDim.y;
  int wg = blockIdx.y * gx + blockIdx.x;
  wg = (wg & 7) * (nwg >> 3) + (wg >> 3);      // XCD chunking (bijective)
  const long arow = (long)(wg / gx) * 128;
  const long bcol = (long)(wg % gx) * 128;

  f32x4 acc[4][4] = {};

  const int c0 = wave * 2, c1 = wave * 2 + 1;
  const int srow0 = c0 * 16 + (lane >> 2);
  const int srow1 = c1 * 16 + (lane >> 2);
  const int scol = (lane & 3) * 8;
  const int l15 = lane & 15, kof = (lane >> 4) * 8;

  auto stage = [&](int buf, int k0) {
    g2lds16(A  + (arow + srow0) * (long)K + k0 + scol, &As[buf][c0 * 512]);
    g2lds16(A  + (arow + srow1) * (long)K + k0 + scol, &As[buf][c1 * 512]);
    g2lds16(Bt + (bcol + srow0) * (long)K + k0 + scol, &Bs[buf][c0 * 512]);
    g2lds16(Bt + (bcol + srow1) * (long)K + k0 + scol, &Bs[buf][c1 * 512]);
  };

  stage(0, 0);
  __syncthreads();                 // drains vmcnt(0): buf0 ready
  int cur = 0;
  for (int k0 = 0; k0 < K; k0 += 32) {
    if (k0 + 32 < K) stage(cur ^ 1, k0 + 32);   // prefetch overlaps compute
    bf16x8 a[4], b[4];
#pragma unroll
    for (int i = 0; i < 4; ++i)
      a[i] = *(const bf16x8*)&As[cur][(wr * 64 + i * 16 + l15) * 32 + kof];
#pragma unroll
    for (int i = 0; i < 4; ++i)
      b[i] = *(const bf16x8*)&Bs[cur][(wc * 64 + i * 16 + l15) * 32 + kof];
#pragma unroll
    for (int mi = 0; mi < 4; ++mi)
#pragma unroll
      for (int ni = 0; ni < 4; ++ni)
        acc[mi][ni] = __builtin_amdgcn_mfma_f32_16x16x32_bf16(
            a[mi], b[ni], acc[mi][ni], 0, 0, 0);
    __syncthreads();               // staged writes landed + all reads done
    cur ^= 1;
  }

#pragma unroll
  for (int mi = 0; mi < 4; ++mi) {
#pragma unroll
    for (int ni = 0; ni < 4; ++ni) {
#pragma unroll
      for (int j = 0; j < 4; ++j) {
        long row = arow + wr * 64 + mi * 16 + (lane >> 4) * 4 + j;
        long col = bcol + wc * 64 + ni * 16 + l15;
        float v = acc[mi][ni][j];
        if constexpr (EPI == 0) {
          int bb = (int)(row >> 11), ss = (int)(row & 2047);
          int hh = (int)(col >> 6) & 15, dd = (int)(col & 63);
          size_t idx = (((size_t)(bb * H_ + hh)) * S_ + ss) * DK_ + dd;
          if (col < 1024) outb[idx]  = (bf16)((v + bias[col]) * scale);
          else            outb2[idx] = (bf16)(v + bias2[col - 1024]);
        } else if constexpr (EPI == 1) {
          size_t idx = (size_t)row * N + col;
          outf[idx] = v + bias[col] + resid[idx];
        } else {
          size_t idx = (size_t)row * N + col;
          float t = v + bias[col];
          outb[idx] = (bf16)(0.5f * t * (1.0f + erff(t * 0.70710678118654752f)));
        }
      }
    }
  }
}

// =====================================================================
// Flash attention, values == K (reference quirk).
// Q pre-scaled by (1/8)*log2(e): softmax runs in exp2 domain (exact).
// Block: 64 q-rows, 4 waves x 16 rows. K-tile = 64 kv. XOR-swizzled LDS.
// This round: K/V LDS double-buffer (1 barrier/tile), local-max
// pre-check (skip shuffle-reduce+rescale in steady tiles), mask-zero
// scan hoisted out of the loop.
// =====================================================================
__global__ __launch_bounds__(256)
void attn_fwd(const bf16* __restrict__ Q, const bf16* __restrict__ Kk,
              const bf16* __restrict__ KT, const int* __restrict__ mask,
              bf16* __restrict__ O) {
  __shared__ __align__(16) char Kl[2][64 * 128];  // swizzled [kv][d]
  __shared__ __align__(16) char Vl[2][64 * 128];  // swizzled [d][kv]
  __shared__ __align__(16) char Pl[4][16 * 128];  // swizzled per-wave P

  const int tid = threadIdx.x, wave = tid >> 6, lane = tid & 63;
  const int bh = blockIdx.y, b = bh >> 4, h = bh & 15;
  const int q0 = blockIdx.x * 64;
  const int l15 = lane & 15, q4 = lane >> 4;

  const bf16* Qp = Q  + (size_t)bh * S_ * DK_;
  const bf16* Kp = Kk + (size_t)bh * S_ * DK_;
  const bf16* Tp = KT + (size_t)bh * DK_ * S_;

  const int qrow = q0 + wave * 16 + l15;
  const bf16x8 qf0 = *(const bf16x8*)&Qp[(size_t)qrow * 64 + q4 * 8];
  const bf16x8 qf1 = *(const bf16x8*)&Qp[(size_t)qrow * 64 + 32 + q4 * 8];

  // mask-zero scan, once per block (mask is [B,1,1,S]: loop-invariant)
  int lz = 0;
  for (int i = tid; i < S_; i += 256) lz |= (mask[b * S_ + i] == 0);
  const bool anyz = __syncthreads_or(lz) != 0;

  // staging coords: 512 chunks of 16B over 2 tiles; 2 chunks/thread/tile
  const int c0 = tid * 2, c1 = tid * 2 + 1;
  const int sr0 = c0 >> 3, sb0 = c0 & 7;
  const int sr1 = c1 >> 3, sb1 = c1 & 7;

  // hoisted swizzled P-store byte offsets (loop-invariant)
  int poff[16];
#pragma unroll
  for (int nt = 0; nt < 4; ++nt)
#pragma unroll
    for (int j = 0; j < 4; ++j) {
      int r = q4 * 4 + j;
      poff[nt * 4 + j] = r * 128 + ((((nt * 16 + l15) * 2)) ^ ((r & 7) << 4));
    }

  bf16x8 onesv;
#pragma unroll
  for (int i = 0; i < 8; ++i) onesv[i] = (bf16)1.0f;

  f32x4 o[4] = {};
  f32x4 ol = {};           // running row-sum (replicated across cols)
  float m_r[4];
#pragma unroll
  for (int j = 0; j < 4; ++j) m_r[j] = -__builtin_inff();

  // prologue: load + write tile 0 into buf0
  bf16x8 a0 = *(const bf16x8*)&Kp[(size_t)sr0 * 64 + sb0 * 8];
  bf16x8 a1 = *(const bf16x8*)&Kp[(size_t)sr1 * 64 + sb1 * 8];
  bf16x8 t0 = *(const bf16x8*)&Tp[(size_t)sr0 * S_ + sb0 * 8];
  bf16x8 t1 = *(const bf16x8*)&Tp[(size_t)sr1 * S_ + sb1 * 8];
  *(bf16x8*)swzp(Kl[0], sr0, sb0 * 16) = a0;
  *(bf16x8*)swzp(Kl[0], sr1, sb1 * 16) = a1;
  *(bf16x8*)swzp(Vl[0], sr0, sb0 * 16) = t0;
  *(bf16x8*)swzp(Vl[0], sr1, sb1 * 16) = t1;
  int cur = 0;

  for (int k0 = 0; k0 < S_; k0 += 64) {
    __syncthreads();   // buf[cur] visible to all waves (lgkmcnt drained)

    // issue next tile's global loads now (landed at write-back below)
    const int nk = k0 + 64;
    if (nk < S_) {
      a0 = *(const bf16x8*)&Kp[(size_t)(nk + sr0) * 64 + sb0 * 8];
      a1 = *(const bf16x8*)&Kp[(size_t)(nk + sr1) * 64 + sb1 * 8];
      t0 = *(const bf16x8*)&Tp[(size_t)sr0 * S_ + nk + sb0 * 8];
      t1 = *(const bf16x8*)&Tp[(size_t)sr1 * S_ + nk + sb1 * 8];
    }

    // scores S' = (Q*log2e/8) K^T
    f32x4 s[4];
#pragma unroll
    for (int nt = 0; nt < 4; ++nt) {
      bf16x8 kf0 = *(const bf16x8*)swzp(Kl[cur], nt * 16 + l15, q4 * 16);
      bf16x8 kf1 = *(const bf16x8*)swzp(Kl[cur], nt * 16 + l15, 64 + q4 * 16);
      f32x4 z = {};
      z     = __builtin_amdgcn_mfma_f32_16x16x32_bf16(qf0, kf0, z, 0, 0, 0);
      s[nt] = __builtin_amdgcn_mfma_f32_16x16x32_bf16(qf1, kf1, z, 0, 0, 0);
    }
    if (anyz) {
#pragma unroll
      for (int nt = 0; nt < 4; ++nt) {
        int m2 = mask[b * S_ + k0 + nt * 16 + l15];
        if (m2 == 0) {
#pragma unroll
          for (int j = 0; j < 4; ++j) s[nt][j] = -1e9f;
        }
      }
    }

    // local (unreduced) per-lane max; pre-check defer-max threshold
    float tm[4];
#pragma unroll
    for (int j = 0; j < 4; ++j)
      tm[j] = fmaxf(fmaxf(s[0][j], s[1][j]), fmaxf(s[2][j], s[3][j]));
    bool ok = true;
#pragma unroll
    for (int j = 0; j < 4; ++j) ok = ok && (tm[j] <= m_r[j] + 8.0f);
    if (!__all(ok)) {
      // full 16-lane butterfly reduce + rescale (rare after tile 0)
#pragma unroll
      for (int d = 1; d < 16; d <<= 1)
#pragma unroll
        for (int j = 0; j < 4; ++j)
          tm[j] = fmaxf(tm[j], __shfl_xor(tm[j], d));
#pragma unroll
      for (int j = 0; j < 4; ++j) {
        float mn = fmaxf(m_r[j], tm[j]);
        float sf = __builtin_amdgcn_exp2f(m_r[j] - mn);
        m_r[j] = mn;
        ol[j] *= sf;
#pragma unroll
        for (int nf = 0; nf < 4; ++nf) o[nf][j] *= sf;
      }
    }

    // P = exp2(S' - m) -> LDS (bf16, swizzled, hoisted offsets)
#pragma unroll
    for (int nt = 0; nt < 4; ++nt)
#pragma unroll
      for (int j = 0; j < 4; ++j)
        *(bf16*)(&Pl[wave][0] + poff[nt * 4 + j]) =
            (bf16)__builtin_amdgcn_exp2f(s[nt][j] - m_r[j]);

    const bf16x8 pf0 = *(const bf16x8*)swzp(Pl[wave], l15, q4 * 16);
    const bf16x8 pf1 = *(const bf16x8*)swzp(Pl[wave], l15, 64 + q4 * 16);

    // row-sum via ones-MFMA (bf16-consistent with PV numerator)
    ol = __builtin_amdgcn_mfma_f32_16x16x32_bf16(pf0, onesv, ol, 0, 0, 0);
    ol = __builtin_amdgcn_mfma_f32_16x16x32_bf16(pf1, onesv, ol, 0, 0, 0);

#pragma unroll
    for (int nf = 0; nf < 4; ++nf) {
      bf16x8 vf0 = *(const bf16x8*)swzp(Vl[cur], nf * 16 + l15, q4 * 16);
      bf16x8 vf1 = *(const bf16x8*)swzp(Vl[cur], nf * 16 + l15, 64 + q4 * 16);
      o[nf] = __builtin_amdgcn_mfma_f32_16x16x32_bf16(pf0, vf0, o[nf], 0, 0, 0);
      o[nf] = __builtin_amdgcn_mfma_f32_16x16x32_bf16(pf1, vf1, o[nf], 0, 0, 0);
    }

    // write next tile into the other buffer (all waves are past the
    // top barrier, so nobody still reads buf[cur^1]'s old contents)
    if (nk < S_) {
      *(bf16x8*)swzp(Kl[cur ^ 1], sr0, sb0 * 16) = a0;
      *(bf16x8*)swzp(Kl[cur ^ 1], sr1, sb1 * 16) = a1;
      *(bf16x8*)swzp(Vl[cur ^ 1], sr0, sb0 * 16) = t0;
      *(bf16x8*)swzp(Vl[cur ^ 1], sr1, sb1 * 16) = t1;
    }
    cur ^= 1;
  }

  // epilogue: scatter to attn buffer [M][D]
#pragma unroll
  for (int nf = 0; nf < 4; ++nf)
#pragma unroll
    for (int j = 0; j < 4; ++j) {
      int row = q0 + wave * 16 + q4 * 4 + j;
      int col = h * 64 + nf * 16 + l15;
      O[((size_t)b * S_ + row) * D_ + col] = (bf16)(o[nf][j] / ol[j]);
    }
}

// =====================================================================
extern "C" void kernel_launch(void* const* d_in, const int* in_sizes, int n_in,
                              void* d_out, int out_size, void* d_ws, size_t ws_size,
                              hipStream_t stream) {
  const float* x    = (const float*)d_in[0];
  const int*   mask = (const int*)d_in[1];
  const float* Wq   = (const float*)d_in[2];
  const float* bq   = (const float*)d_in[3];
  const float* Wk   = (const float*)d_in[4];
  const float* bk   = (const float*)d_in[5];
  // d_in[6]=Wv, d_in[7]=bv: dead code in the reference (value == key)
  const float* Wo   = (const float*)d_in[8];
  const float* bo   = (const float*)d_in[9];
  const float* ln1g = (const float*)d_in[10];
  const float* ln1b = (const float*)d_in[11];
  const float* W1   = (const float*)d_in[12];
  const float* b1   = (const float*)d_in[13];
  const float* W2   = (const float*)d_in[14];
  const float* b2   = (const float*)d_in[15];
  const float* ln2g = (const float*)d_in[16];
  const float* ln2b = (const float*)d_in[17];
  float* out = (float*)d_out;

  char* w = (char*)d_ws;
  auto alloc = [&](size_t bytes) {
    void* p = (void*)w;
    w += (bytes + 255) & ~(size_t)255;
    return p;
  };
  bf16* xln  = (bf16*)alloc((size_t)M_ * D_ * 2);
  bf16* WqkT = (bf16*)alloc((size_t)2 * D_ * D_ * 2);
  bf16* WoT  = (bf16*)alloc((size_t)D_ * D_ * 2);
  bf16* W1T  = (bf16*)alloc((size_t)D_ * DFF_ * 2);
  bf16* W2T  = (bf16*)alloc((size_t)D_ * DFF_ * 2);
  bf16* Qt   = (bf16*)alloc((size_t)M_ * D_ * 2);
  bf16* Kt   = (bf16*)alloc((size_t)M_ * D_ * 2);
  bf16* KTt  = (bf16*)alloc((size_t)M_ * D_ * 2);
  bf16* attn = (bf16*)alloc((size_t)M_ * D_ * 2);
  float* x2  = (float*)alloc((size_t)M_ * D_ * 4);
  bf16* h2   = (bf16*)alloc((size_t)M_ * D_ * 2);
  bf16* act  = (bf16*)alloc((size_t)M_ * DFF_ * 2);

  tcast_all<<<11264, dim3(32, 8), 0, stream>>>(Wq, Wk, Wo, W1, W2,
                                               WqkT, WoT, W1T, W2T);

  ln_fwd<<<M_, 256, 0, stream>>>(x, ln1g, ln1b, xln);

  // fused Q+K projection; Q scale (1/8)*log2e folded (exp2-domain softmax)
  gemm_bt<0><<<dim3(16, 64), 256, 0, stream>>>(
      xln, WqkT, M_, 2048, 1024, bq, bk, nullptr,
      0.125f * 1.4426950408889634f, nullptr, Qt, Kt);

  ktrans<<<dim3(S_ / 64, B_ * H_), 256, 0, stream>>>(Kt, KTt);

  attn_fwd<<<dim3(S_ / 64, B_ * H_), 256, 0, stream>>>(Qt, Kt, KTt, mask, attn);

  // x2 = x + attn @ Wo + bo   (f32)
  gemm_bt<1><<<dim3(8, 64), 256, 0, stream>>>(attn, WoT, M_, 1024, 1024,
                                              bo, nullptr, x, 1.0f,
                                              x2, nullptr, nullptr);

  ln_fwd<<<M_, 256, 0, stream>>>(x2, ln2g, ln2b, h2);

  // act = gelu(h2 @ W1 + b1)  (bf16)
  gemm_bt<2><<<dim3(32, 64), 256, 0, stream>>>(h2, W1T, M_, 4096, 1024,
                                               b1, nullptr, nullptr, 1.0f,
                                               nullptr, act, nullptr);
  // out = x2 + act @ W2 + b2  (f32)
  gemm_bt<1><<<dim3(8, 64), 256, 0, stream>>>(act, W2T, M_, 1024, 4096,
                                              b2, nullptr, x2, 1.0f,
                                              out, nullptr, nullptr);
}